// Round 1
// baseline (272.060 us; speedup 1.0000x reference)
//
#include <hip/hip_runtime.h>

// DeepPoly ReLU relaxation, elementwise over N neurons.
//   clamped_alpha = clip(alpha, 0, 1)
//   slope   = max(ub/(ub-lb), 0)
//   out_lb  = (ub < 0) ? lb*0 : lb*clamped_alpha
//   out_ub  = (lb > 0) ? ub*1 + 0 : ub*slope + (-(slope*lb))
// Memory-bound: 12 B read + 8 B written per neuron.

__device__ __forceinline__ void relax_one(float lb, float ub, float al,
                                          float& olb, float& oub) {
    float ca    = fminf(fmaxf(al, 0.0f), 1.0f);
    float slope = fmaxf(ub / (ub - lb), 0.0f);
    // Mirror reference arithmetic order exactly (no algebraic refactor):
    float uc_bias = -(slope * lb);
    float uc_diag = (lb > 0.0f) ? 1.0f : slope;
    float lc_diag = (ub < 0.0f) ? 0.0f : ca;
    float ub_bias = (lb > 0.0f) ? 0.0f : uc_bias;
    olb = lb * lc_diag;
    oub = ub * uc_diag + ub_bias;
}

__global__ __launch_bounds__(256) void verify_relu_v4(
    const float4* __restrict__ lb4,
    const float4* __restrict__ ub4,
    const float4* __restrict__ al4,
    float4* __restrict__ out_lb4,
    float4* __restrict__ out_ub4,
    int n4)
{
    int i = blockIdx.x * blockDim.x + threadIdx.x;
    if (i >= n4) return;
    float4 lb = lb4[i];
    float4 ub = ub4[i];
    float4 al = al4[i];
    float4 olb, oub;
    relax_one(lb.x, ub.x, al.x, olb.x, oub.x);
    relax_one(lb.y, ub.y, al.y, olb.y, oub.y);
    relax_one(lb.z, ub.z, al.z, olb.z, oub.z);
    relax_one(lb.w, ub.w, al.w, olb.w, oub.w);
    out_lb4[i] = olb;
    out_ub4[i] = oub;
}

// Scalar tail (only used if n % 4 != 0; N=16777216 is divisible by 4).
__global__ __launch_bounds__(64) void verify_relu_tail(
    const float* __restrict__ lb,
    const float* __restrict__ ub,
    const float* __restrict__ al,
    float* __restrict__ out_lb,
    float* __restrict__ out_ub,
    int start, int n)
{
    int i = start + blockIdx.x * blockDim.x + threadIdx.x;
    if (i >= n) return;
    float olb, oub;
    relax_one(lb[i], ub[i], al[i], olb, oub);
    out_lb[i] = olb;
    out_ub[i] = oub;
}

extern "C" void kernel_launch(void* const* d_in, const int* in_sizes, int n_in,
                              void* d_out, int out_size, void* d_ws, size_t ws_size,
                              hipStream_t stream) {
    const float* lb = (const float*)d_in[0];
    const float* ub = (const float*)d_in[1];
    const float* al = (const float*)d_in[2];
    float* out_lb = (float*)d_out;
    int n = in_sizes[0];
    float* out_ub = out_lb + n;

    int n4 = n / 4;
    if (n4 > 0) {
        int threads = 256;
        int blocks = (n4 + threads - 1) / threads;
        verify_relu_v4<<<blocks, threads, 0, stream>>>(
            (const float4*)lb, (const float4*)ub, (const float4*)al,
            (float4*)out_lb, (float4*)out_ub, n4);
    }
    int tail_start = n4 * 4;
    if (tail_start < n) {
        int tail_n = n - tail_start;
        int blocks = (tail_n + 63) / 64;
        verify_relu_tail<<<blocks, 64, 0, stream>>>(
            lb, ub, al, out_lb, out_ub, tail_start, n);
    }
}

// Round 3
// 256.699 us; speedup vs baseline: 1.0598x; 1.0598x over previous
//
#include <hip/hip_runtime.h>

// DeepPoly ReLU relaxation, elementwise over N neurons.
//   clamped_alpha = clip(alpha, 0, 1)
//   slope   = max(ub/(ub-lb), 0)
//   out_lb  = (ub < 0) ? 0 : lb*clamped_alpha
//   out_ub  = (lb > 0) ? ub : ub*slope + (-(slope*lb))
// Memory-bound streaming op: 12 B read + 8 B written per neuron.
// R1->R2: HIP float4 is a struct; nontemporal builtins need a native clang
// vector type. Use ext_vector_type(4) float.

typedef float vfloat4 __attribute__((ext_vector_type(4)));

__device__ __forceinline__ void relax_one(float lb, float ub, float al,
                                          float& olb, float& oub) {
    float ca    = fminf(fmaxf(al, 0.0f), 1.0f);
    float slope = fmaxf(ub / (ub - lb), 0.0f);
    // Mirror reference arithmetic order exactly (no algebraic refactor):
    float uc_bias = -(slope * lb);
    float uc_diag = (lb > 0.0f) ? 1.0f : slope;
    float lc_diag = (ub < 0.0f) ? 0.0f : ca;
    float ub_bias = (lb > 0.0f) ? 0.0f : uc_bias;
    olb = lb * lc_diag;
    oub = ub * uc_diag + ub_bias;
}

__device__ __forceinline__ void relax_vec4(const vfloat4& lb, const vfloat4& ub,
                                           const vfloat4& al,
                                           vfloat4& olb, vfloat4& oub) {
#pragma unroll
    for (int c = 0; c < 4; ++c) {
        float olbc, oubc;
        relax_one(lb[c], ub[c], al[c], olbc, oubc);
        olb[c] = olbc;
        oub[c] = oubc;
    }
}

constexpr int THREADS = 256;
constexpr int K = 4;  // float4 chunks per thread

__global__ __launch_bounds__(THREADS) void verify_relu_v4u(
    const vfloat4* __restrict__ lb4,
    const vfloat4* __restrict__ ub4,
    const vfloat4* __restrict__ al4,
    vfloat4* __restrict__ out_lb4,
    vfloat4* __restrict__ out_ub4,
    int n4)
{
    int base = blockIdx.x * (THREADS * K) + threadIdx.x;

    if (base + (K - 1) * THREADS < n4) {
        // Fast path: all K chunks in-bounds. Issue all 3*K loads before
        // any dependent use -> 12 outstanding 16B loads per thread.
        vfloat4 lb[K], ub[K], al[K];
#pragma unroll
        for (int j = 0; j < K; ++j) {
            int i = base + j * THREADS;
            lb[j] = __builtin_nontemporal_load(&lb4[i]);
            ub[j] = __builtin_nontemporal_load(&ub4[i]);
            al[j] = __builtin_nontemporal_load(&al4[i]);
        }
#pragma unroll
        for (int j = 0; j < K; ++j) {
            int i = base + j * THREADS;
            vfloat4 olb, oub;
            relax_vec4(lb[j], ub[j], al[j], olb, oub);
            __builtin_nontemporal_store(olb, &out_lb4[i]);
            __builtin_nontemporal_store(oub, &out_ub4[i]);
        }
    } else {
        // Boundary block: per-chunk bounds check.
#pragma unroll
        for (int j = 0; j < K; ++j) {
            int i = base + j * THREADS;
            if (i < n4) {
                vfloat4 lb = __builtin_nontemporal_load(&lb4[i]);
                vfloat4 ub = __builtin_nontemporal_load(&ub4[i]);
                vfloat4 al = __builtin_nontemporal_load(&al4[i]);
                vfloat4 olb, oub;
                relax_vec4(lb, ub, al, olb, oub);
                __builtin_nontemporal_store(olb, &out_lb4[i]);
                __builtin_nontemporal_store(oub, &out_ub4[i]);
            }
        }
    }
}

// Scalar tail (only used if n % 4 != 0; N=16777216 is divisible by 4).
__global__ __launch_bounds__(64) void verify_relu_tail(
    const float* __restrict__ lb,
    const float* __restrict__ ub,
    const float* __restrict__ al,
    float* __restrict__ out_lb,
    float* __restrict__ out_ub,
    int start, int n)
{
    int i = start + blockIdx.x * blockDim.x + threadIdx.x;
    if (i >= n) return;
    float olb, oub;
    relax_one(lb[i], ub[i], al[i], olb, oub);
    out_lb[i] = olb;
    out_ub[i] = oub;
}

extern "C" void kernel_launch(void* const* d_in, const int* in_sizes, int n_in,
                              void* d_out, int out_size, void* d_ws, size_t ws_size,
                              hipStream_t stream) {
    const float* lb = (const float*)d_in[0];
    const float* ub = (const float*)d_in[1];
    const float* al = (const float*)d_in[2];
    float* out_lb = (float*)d_out;
    int n = in_sizes[0];
    float* out_ub = out_lb + n;

    int n4 = n / 4;
    if (n4 > 0) {
        int per_block = THREADS * K;
        int blocks = (n4 + per_block - 1) / per_block;
        verify_relu_v4u<<<blocks, THREADS, 0, stream>>>(
            (const vfloat4*)lb, (const vfloat4*)ub, (const vfloat4*)al,
            (vfloat4*)out_lb, (vfloat4*)out_ub, n4);
    }
    int tail_start = n4 * 4;
    if (tail_start < n) {
        int tail_n = n - tail_start;
        int blocks = (tail_n + 63) / 64;
        verify_relu_tail<<<blocks, 64, 0, stream>>>(
            lb, ub, al, out_lb, out_ub, tail_start, n);
    }
}